// Round 20
// baseline (954.490 us; speedup 1.0000x reference)
//
#include <hip/hip_runtime.h>
#include <hip/hip_fp16.h>

// Problem: B=64, T=512, IN=1024, H=1024, NH=4, HD=256, NG=3
// out h: [B,T,H] then hn: [1,B,H]  (fp32)

typedef _Float16 f16x8 __attribute__((ext_vector_type(8)));
typedef float    f32x4 __attribute__((ext_vector_type(4)));

#define AS1 __attribute__((address_space(1)))
#define AS3 __attribute__((address_space(3)))

__device__ __forceinline__ void async_ld16(const void* g, void* l) {
    __builtin_amdgcn_global_load_lds((const AS1 void*)g, (AS3 void*)l, 16, 0, 0);
}

#if defined(__has_builtin)
#if __has_builtin(__builtin_amdgcn_rcpf)
#define RCPF(x) __builtin_amdgcn_rcpf(x)
#endif
#endif
#ifndef RCPF
#define RCPF(x) (1.f / (x))
#endif

// gates with v_rcp_f32 instead of IEEE divide (~1 ulp; threshold 2e-2)
__device__ __forceinline__ float sigmoidf_(float x) {
    return RCPF(1.f + __expf(-x));
}
__device__ __forceinline__ float tanhf_(float x) {
    float e = __expf(-2.f * fabsf(x));
    float r = (1.f - e) * RCPF(1.f + e);
    return copysignf(r, x);
}

// ---- input f32 -> f16 (vectorized) ----
__global__ __launch_bounds__(256) void cast_to_f16(const float* __restrict__ in,
                                                   _Float16* __restrict__ out, int n8) {
    int i = blockIdx.x * 256 + threadIdx.x;
    if (i >= n8) return;
    const float4* p = (const float4*)in;
    float4 a = p[2 * i], b = p[2 * i + 1];
    f16x8 r;
    r[0] = (_Float16)a.x; r[1] = (_Float16)a.y; r[2] = (_Float16)a.z; r[3] = (_Float16)a.w;
    r[4] = (_Float16)b.x; r[5] = (_Float16)b.y; r[6] = (_Float16)b.z; r[7] = (_Float16)b.w;
    *(f16x8*)(out + (size_t)i * 8) = r;
}

// ---- W [1024,3072] f32 -> W^T [3072,1024] f16 ----
__global__ __launch_bounds__(256) void transpose_cast(const float* __restrict__ W,
                                                      _Float16* __restrict__ WT) {
    __shared__ float tile[32][33];
    const int tx = threadIdx.x, ty = threadIdx.y;
    const int n0 = blockIdx.x * 32, k0 = blockIdx.y * 32;
#pragma unroll
    for (int j = 0; j < 32; j += 8)
        tile[ty + j][tx] = W[(size_t)(k0 + ty + j) * 3072 + n0 + tx];
    __syncthreads();
#pragma unroll
    for (int j = 0; j < 32; j += 8)
        WT[(size_t)(n0 + ty + j) * 1024 + k0 + tx] = (_Float16)tile[tx][ty + j];
}

// ---- GEMM: Wx[t][b][head*3+g][o] f16 = (input @ W) + bW + bR ----
// Grid = 6144 linear blocks. XCD-chunked swizzle (T1, bijective: 6144 = 8*768):
// each XCD owns 768 consecutive remapped ids, decoded N-major (3 N-tiles x 256
// M-tiles) -> per-XCD B-slab = 3*128 cols * 1024 k * f16 = 768 KB, resident in
// that XCD's 4 MB L2 across the whole M sweep (was L3-fed before).
__global__ __launch_bounds__(256) void gemm_wx(const _Float16* __restrict__ A,
                                               const _Float16* __restrict__ BT,
                                               const float* __restrict__ bW,
                                               const float* __restrict__ bR,
                                               _Float16* __restrict__ Wx) {
    __shared__ _Float16 As[128 * 32];
    __shared__ _Float16 Bs[128 * 32];
    const int tid  = threadIdx.x;
    const int wave = tid >> 6, lane = tid & 63;

    const int wgid  = blockIdx.x;
    const int newid = (wgid & 7) * 768 + (wgid >> 3);  // XCD chunk
    const int m0 = (newid & 255) * 128;                // N-major decode
    const int n0 = (newid >> 8) * 128;

    const int wm = (wave >> 1) * 64, wn = (wave & 1) * 64;
    const int r16 = lane & 15, kq = lane >> 4;

    f32x4 acc[4][4];
#pragma unroll
    for (int m = 0; m < 4; m++)
#pragma unroll
        for (int n = 0; n < 4; n++) acc[m][n] = (f32x4){0.f, 0.f, 0.f, 0.f};

    const int srow = wave * 32 + (lane >> 2);
    const int scol = (lane & 3) * 8;

    for (int kt = 0; kt < 32; kt++) {
        const int k0 = kt * 32;
#pragma unroll
        for (int j = 0; j < 2; j++) {
            async_ld16(A  + (size_t)(m0 + srow + j * 16) * 1024 + k0 + scol,
                       As + (wave * 32 + j * 16) * 32);
            async_ld16(BT + (size_t)(n0 + srow + j * 16) * 1024 + k0 + scol,
                       Bs + (wave * 32 + j * 16) * 32);
        }
        __syncthreads();
        f16x8 af[4], bf[4];
#pragma unroll
        for (int m = 0; m < 4; m++) af[m] = *(const f16x8*)(As + (wm + m * 16 + r16) * 32 + kq * 8);
#pragma unroll
        for (int n = 0; n < 4; n++) bf[n] = *(const f16x8*)(Bs + (wn + n * 16 + r16) * 32 + kq * 8);
#pragma unroll
        for (int m = 0; m < 4; m++)
#pragma unroll
            for (int n = 0; n < 4; n++)
                acc[m][n] = __builtin_amdgcn_mfma_f32_16x16x32_f16(af[m], bf[n], acc[m][n], 0, 0, 0);
        __syncthreads();
    }

#pragma unroll
    for (int m = 0; m < 4; m++) {
        const int row0 = m0 + wm + m * 16 + (lane >> 4) * 4;
#pragma unroll
        for (int n = 0; n < 4; n++) {
            const int col  = n0 + wn + n * 16 + r16;
            const int g    = col >> 10, head = (col >> 8) & 3, o = col & 255;
            const float bias = bW[col] + bR[head * 768 + g * 256 + o];
#pragma unroll
            for (int q = 0; q < 4; q++) {
                const int rr = row0 + q;
                const int t = rr & 511, bb = rr >> 9;
                Wx[(((size_t)t * 64 + bb) * 12 + head * 3 + g) * 256 + o] =
                    (_Float16)(acc[m][n][q] + bias);
            }
        }
    }
}

// ---- MFMA persistent scan: 256 blocks = (b, head); 512 thr = 8 waves (2/SIMD).
// Best measured structure (R19: 683 µs): h broadcast into 16 A-rows, lane-local
// gates; 7 k-tiles of R in regs + kt7 streamed from LDS (keeps acc in ARCH VGPRs;
// R18: 8-in-regs pushes acc to AGPR and gates pay v_accvgpr_read); VMEM at step
// top (R17: barrier vmcnt-drain fix, -8%); pipelined A-reads; rcp gates; Wx f16;
// b128-vectorized R staging.
__global__ __launch_bounds__(512) void scan_mfma(const float* __restrict__ R,
                                                 const _Float16* __restrict__ Wx,
                                                 float* __restrict__ out) {
    __shared__ _Float16 Rbuf[3 * 256 * 40];  // [g][o][40]: 32 k + 8 pad (16B-aligned)
    __shared__ _Float16 h16[2 * 256];        // h double buffer

    const int bx = blockIdx.x;
    const int head = bx >> 6, b = bx & 63;
    const int t0 = threadIdx.x;
    const int w = t0 >> 6, l = t0 & 63;
    const int c = l & 15, kq = l >> 4;
    const int o0 = w * 32;

    // ---- stage R in 8 chunks of 32 k (vectorized b128 writes); Bf kt 0..6 in regs ----
    f16x8 Bf[3][2][7];
#pragma unroll
    for (int kt = 0; kt < 8; kt++) {
        __syncthreads();  // protect prior chunk's reads before overwrite
        for (int item = t0; item < 3072; item += 512) {
            const int q = item / 768;
            const int rem = item - q * 768;
            const int g = rem >> 8, o = rem & 255;
            const float* rp = R + (((size_t)head * 256 + kt * 32 + q * 8) * 3 + g) * 256 + o;
            f16x8 v;
#pragma unroll
            for (int j = 0; j < 8; j++) v[j] = (_Float16)rp[(size_t)j * 768];
            *(f16x8*)(Rbuf + ((size_t)(g * 256 + o)) * 40 + q * 8) = v;
        }
        __syncthreads();
        if (kt < 7) {
#pragma unroll
            for (int g = 0; g < 3; g++)
#pragma unroll
                for (int ot = 0; ot < 2; ot++)
                    Bf[g][ot][kt] =
                        *(const f16x8*)(Rbuf + ((size_t)(g * 256 + o0 + ot * 16 + c)) * 40 + kq * 8);
        }
    }

    h16[t0] = (_Float16)0.f;  // 512 threads zero both 256-entry buffers

    float hprev[2] = {0.f, 0.f};
    float* outb = out + ((size_t)b * 512) * 1024 + head * 256;
    float* hnp  = out + (size_t)64 * 512 * 1024 + b * 1024 + head * 256;

    float wxc[3][2];
#pragma unroll
    for (int g = 0; g < 3; g++)
#pragma unroll
        for (int o2 = 0; o2 < 2; o2++)
            wxc[g][o2] =
                (float)Wx[(((size_t)0 * 64 + b) * 12 + head * 3 + g) * 256 + o0 + o2 * 16 + c];
    __syncthreads();

    int cur = 0;
    for (int t = 0; t < 512; t++) {
        const _Float16* hc = h16 + cur * 256;

        // ---- step top (fresh after barrier): issue ALL VMEM first ----
        if (t > 0 && kq == 0) {
#pragma unroll
            for (int o2 = 0; o2 < 2; o2++)
                outb[(size_t)(t - 1) * 1024 + o0 + o2 * 16 + c] = hprev[o2];
        }
        float wxn[3][2];
        if (t < 511) {
#pragma unroll
            for (int g = 0; g < 3; g++)
#pragma unroll
                for (int o2 = 0; o2 < 2; o2++)
                    wxn[g][o2] = (float)Wx[(((size_t)(t + 1) * 64 + b) * 12 + head * 3 + g) * 256 +
                                           o0 + o2 * 16 + c];
        } else {
            wxn[0][0] = wxn[0][1] = wxn[1][0] = wxn[1][1] = wxn[2][0] = wxn[2][1] = 0.f;
        }

        // ---- LDS: loop-invariant B-kt7 frags + pipelined A-frags ----
        f16x8 Bs7[3][2];
#pragma unroll
        for (int g = 0; g < 3; g++)
#pragma unroll
            for (int ot = 0; ot < 2; ot++)
                Bs7[g][ot] =
                    *(const f16x8*)(Rbuf + ((size_t)(g * 256 + o0 + ot * 16 + c)) * 40 + kq * 8);
        f16x8 Af0 = *(const f16x8*)(hc + 0 * 32 + kq * 8);

        f32x4 acc[3][2];
#pragma unroll
        for (int g = 0; g < 3; g++)
#pragma unroll
            for (int ot = 0; ot < 2; ot++) acc[g][ot] = (f32x4){0.f, 0.f, 0.f, 0.f};

#pragma unroll
        for (int kt = 0; kt < 8; kt++) {
            f16x8 Af1;
            if (kt < 7) Af1 = *(const f16x8*)(hc + (kt + 1) * 32 + kq * 8);
#pragma unroll
            for (int g = 0; g < 3; g++)
#pragma unroll
                for (int ot = 0; ot < 2; ot++)
                    acc[g][ot] = __builtin_amdgcn_mfma_f32_16x16x32_f16(
                        Af0, (kt < 7) ? Bf[g][ot][kt] : Bs7[g][ot], acc[g][ot], 0, 0, 0);
            Af0 = Af1;
        }

        // ---- gates (lane-replicated); h kept in regs, LDS write only ----
        _Float16* hw = h16 + (cur ^ 1) * 256;
#pragma unroll
        for (int o2 = 0; o2 < 2; o2++) {
            const float z = sigmoidf_(wxc[0][o2] + acc[0][o2][0]);
            const float r = sigmoidf_(wxc[1][o2] + acc[1][o2][0]);
            const float n = tanhf_(wxc[2][o2] + r * acc[2][o2][0]);
            const float h = n + z * (hprev[o2] - n);
            hprev[o2] = h;
            if (kq == 0) hw[o0 + o2 * 16 + c] = (_Float16)h;
        }
#pragma unroll
        for (int g = 0; g < 3; g++)
#pragma unroll
            for (int o2 = 0; o2 < 2; o2++) wxc[g][o2] = wxn[g][o2];

        __syncthreads();
        cur ^= 1;
    }
    // final stores: h(511) + hn
    if (kq == 0) {
#pragma unroll
        for (int o2 = 0; o2 < 2; o2++) {
            outb[(size_t)511 * 1024 + o0 + o2 * 16 + c] = hprev[o2];
            hnp[o0 + o2 * 16 + c] = hprev[o2];
        }
    }
}

extern "C" void kernel_launch(void* const* d_in, const int* in_sizes, int n_in,
                              void* d_out, int out_size, void* d_ws, size_t ws_size,
                              hipStream_t stream) {
    (void)in_sizes; (void)n_in; (void)out_size; (void)ws_size;
    const float* inp = (const float*)d_in[0];
    const float* W   = (const float*)d_in[1];
    const float* bW  = (const float*)d_in[2];
    const float* R   = (const float*)d_in[3];
    const float* bR  = (const float*)d_in[4];
    float* out = (float*)d_out;

    // ws layout: A16 (64 MiB) | WT (6 MiB) | Wx f16 (192 MiB)
    _Float16* A16 = (_Float16*)d_ws;
    _Float16* WT  = (_Float16*)((char*)d_ws + 67108864);
    _Float16* Wx  = (_Float16*)((char*)d_ws + 73400320);

    cast_to_f16<<<16384, 256, 0, stream>>>(inp, A16, 4194304);
    transpose_cast<<<dim3(96, 32), dim3(32, 8), 0, stream>>>(W, WT);
    gemm_wx<<<6144, 256, 0, stream>>>(A16, WT, bW, bR, Wx);
    scan_mfma<<<256, 512, 0, stream>>>(R, Wx, out);
}

// Round 21
// 934.325 us; speedup vs baseline: 1.0216x; 1.0216x over previous
//
#include <hip/hip_runtime.h>
#include <hip/hip_fp16.h>

// Problem: B=64, T=512, IN=1024, H=1024, NH=4, HD=256, NG=3
// out h: [B,T,H] then hn: [1,B,H]  (fp32)

typedef _Float16 f16x8 __attribute__((ext_vector_type(8)));
typedef float    f32x4 __attribute__((ext_vector_type(4)));

#define AS1 __attribute__((address_space(1)))
#define AS3 __attribute__((address_space(3)))

__device__ __forceinline__ void async_ld16(const void* g, void* l) {
    __builtin_amdgcn_global_load_lds((const AS1 void*)g, (AS3 void*)l, 16, 0, 0);
}

#if defined(__has_builtin)
#if __has_builtin(__builtin_amdgcn_rcpf)
#define RCPF(x) __builtin_amdgcn_rcpf(x)
#endif
#endif
#ifndef RCPF
#define RCPF(x) (1.f / (x))
#endif

// gates with v_rcp_f32 instead of IEEE divide (~1 ulp; threshold 2e-2)
__device__ __forceinline__ float sigmoidf_(float x) {
    return RCPF(1.f + __expf(-x));
}
__device__ __forceinline__ float tanhf_(float x) {
    float e = __expf(-2.f * fabsf(x));
    float r = (1.f - e) * RCPF(1.f + e);
    return copysignf(r, x);
}

// ---- input f32 -> f16 (vectorized) ----
__global__ __launch_bounds__(256) void cast_to_f16(const float* __restrict__ in,
                                                   _Float16* __restrict__ out, int n8) {
    int i = blockIdx.x * 256 + threadIdx.x;
    if (i >= n8) return;
    const float4* p = (const float4*)in;
    float4 a = p[2 * i], b = p[2 * i + 1];
    f16x8 r;
    r[0] = (_Float16)a.x; r[1] = (_Float16)a.y; r[2] = (_Float16)a.z; r[3] = (_Float16)a.w;
    r[4] = (_Float16)b.x; r[5] = (_Float16)b.y; r[6] = (_Float16)b.z; r[7] = (_Float16)b.w;
    *(f16x8*)(out + (size_t)i * 8) = r;
}

// ---- W [1024,3072] f32 -> W^T [3072,1024] f16 ----
__global__ __launch_bounds__(256) void transpose_cast(const float* __restrict__ W,
                                                      _Float16* __restrict__ WT) {
    __shared__ float tile[32][33];
    const int tx = threadIdx.x, ty = threadIdx.y;
    const int n0 = blockIdx.x * 32, k0 = blockIdx.y * 32;
#pragma unroll
    for (int j = 0; j < 32; j += 8)
        tile[ty + j][tx] = W[(size_t)(k0 + ty + j) * 3072 + n0 + tx];
    __syncthreads();
#pragma unroll
    for (int j = 0; j < 32; j += 8)
        WT[(size_t)(n0 + ty + j) * 1024 + k0 + tx] = (_Float16)tile[tx][ty + j];
}

// ---- GEMM: Wx[t][b][head*3+g][o] f16 = (input @ W) + bW + bR ----
// Linear grid (24 N-tiles x 256 M-tiles), M-major neighboring: R20 showed the
// XCD N-major swizzle LOSES A-row/C-store locality worth more than B residency.
__global__ __launch_bounds__(256) void gemm_wx(const _Float16* __restrict__ A,
                                               const _Float16* __restrict__ BT,
                                               const float* __restrict__ bW,
                                               const float* __restrict__ bR,
                                               _Float16* __restrict__ Wx) {
    __shared__ _Float16 As[128 * 32];
    __shared__ _Float16 Bs[128 * 32];
    const int tid  = threadIdx.x;
    const int wave = tid >> 6, lane = tid & 63;
    const int m0 = blockIdx.y * 128, n0 = blockIdx.x * 128;
    const int wm = (wave >> 1) * 64, wn = (wave & 1) * 64;
    const int r16 = lane & 15, kq = lane >> 4;

    f32x4 acc[4][4];
#pragma unroll
    for (int m = 0; m < 4; m++)
#pragma unroll
        for (int n = 0; n < 4; n++) acc[m][n] = (f32x4){0.f, 0.f, 0.f, 0.f};

    const int srow = wave * 32 + (lane >> 2);
    const int scol = (lane & 3) * 8;

    for (int kt = 0; kt < 32; kt++) {
        const int k0 = kt * 32;
#pragma unroll
        for (int j = 0; j < 2; j++) {
            async_ld16(A  + (size_t)(m0 + srow + j * 16) * 1024 + k0 + scol,
                       As + (wave * 32 + j * 16) * 32);
            async_ld16(BT + (size_t)(n0 + srow + j * 16) * 1024 + k0 + scol,
                       Bs + (wave * 32 + j * 16) * 32);
        }
        __syncthreads();
        f16x8 af[4], bf[4];
#pragma unroll
        for (int m = 0; m < 4; m++) af[m] = *(const f16x8*)(As + (wm + m * 16 + r16) * 32 + kq * 8);
#pragma unroll
        for (int n = 0; n < 4; n++) bf[n] = *(const f16x8*)(Bs + (wn + n * 16 + r16) * 32 + kq * 8);
#pragma unroll
        for (int m = 0; m < 4; m++)
#pragma unroll
            for (int n = 0; n < 4; n++)
                acc[m][n] = __builtin_amdgcn_mfma_f32_16x16x32_f16(af[m], bf[n], acc[m][n], 0, 0, 0);
        __syncthreads();
    }

#pragma unroll
    for (int m = 0; m < 4; m++) {
        const int row0 = m0 + wm + m * 16 + (lane >> 4) * 4;
#pragma unroll
        for (int n = 0; n < 4; n++) {
            const int col  = n0 + wn + n * 16 + r16;
            const int g    = col >> 10, head = (col >> 8) & 3, o = col & 255;
            const float bias = bW[col] + bR[head * 768 + g * 256 + o];
#pragma unroll
            for (int q = 0; q < 4; q++) {
                const int rr = row0 + q;
                const int t = rr & 511, bb = rr >> 9;
                Wx[(((size_t)t * 64 + bb) * 12 + head * 3 + g) * 256 + o] =
                    (_Float16)(acc[m][n][q] + bias);
            }
        }
    }
}

// ---- MFMA persistent scan: 256 blocks = (b, head); 512 thr = 8 waves (2/SIMD).
// Best measured structure (R19: 683 µs): h broadcast into 16 A-rows, lane-local
// gates; 7 k-tiles of R in regs + kt7 streamed from LDS (keeps acc in ARCH VGPRs;
// R18: 8-in-regs pushes acc to AGPR and gates pay v_accvgpr_read); VMEM at step
// top (R17: barrier vmcnt-drain fix, -8%); pipelined A-reads; rcp gates; Wx f16;
// b128-vectorized R staging.
__global__ __launch_bounds__(512) void scan_mfma(const float* __restrict__ R,
                                                 const _Float16* __restrict__ Wx,
                                                 float* __restrict__ out) {
    __shared__ _Float16 Rbuf[3 * 256 * 40];  // [g][o][40]: 32 k + 8 pad (16B-aligned)
    __shared__ _Float16 h16[2 * 256];        // h double buffer

    const int bx = blockIdx.x;
    const int head = bx >> 6, b = bx & 63;
    const int t0 = threadIdx.x;
    const int w = t0 >> 6, l = t0 & 63;
    const int c = l & 15, kq = l >> 4;
    const int o0 = w * 32;

    // ---- stage R in 8 chunks of 32 k (vectorized b128 writes); Bf kt 0..6 in regs ----
    f16x8 Bf[3][2][7];
#pragma unroll
    for (int kt = 0; kt < 8; kt++) {
        __syncthreads();  // protect prior chunk's reads before overwrite
        for (int item = t0; item < 3072; item += 512) {
            const int q = item / 768;
            const int rem = item - q * 768;
            const int g = rem >> 8, o = rem & 255;
            const float* rp = R + (((size_t)head * 256 + kt * 32 + q * 8) * 3 + g) * 256 + o;
            f16x8 v;
#pragma unroll
            for (int j = 0; j < 8; j++) v[j] = (_Float16)rp[(size_t)j * 768];
            *(f16x8*)(Rbuf + ((size_t)(g * 256 + o)) * 40 + q * 8) = v;
        }
        __syncthreads();
        if (kt < 7) {
#pragma unroll
            for (int g = 0; g < 3; g++)
#pragma unroll
                for (int ot = 0; ot < 2; ot++)
                    Bf[g][ot][kt] =
                        *(const f16x8*)(Rbuf + ((size_t)(g * 256 + o0 + ot * 16 + c)) * 40 + kq * 8);
        }
    }

    h16[t0] = (_Float16)0.f;  // 512 threads zero both 256-entry buffers

    float hprev[2] = {0.f, 0.f};
    float* outb = out + ((size_t)b * 512) * 1024 + head * 256;
    float* hnp  = out + (size_t)64 * 512 * 1024 + b * 1024 + head * 256;

    float wxc[3][2];
#pragma unroll
    for (int g = 0; g < 3; g++)
#pragma unroll
        for (int o2 = 0; o2 < 2; o2++)
            wxc[g][o2] =
                (float)Wx[(((size_t)0 * 64 + b) * 12 + head * 3 + g) * 256 + o0 + o2 * 16 + c];
    __syncthreads();

    int cur = 0;
    for (int t = 0; t < 512; t++) {
        const _Float16* hc = h16 + cur * 256;

        // ---- step top (fresh after barrier): issue ALL VMEM first ----
        if (t > 0 && kq == 0) {
#pragma unroll
            for (int o2 = 0; o2 < 2; o2++)
                outb[(size_t)(t - 1) * 1024 + o0 + o2 * 16 + c] = hprev[o2];
        }
        float wxn[3][2];
        if (t < 511) {
#pragma unroll
            for (int g = 0; g < 3; g++)
#pragma unroll
                for (int o2 = 0; o2 < 2; o2++)
                    wxn[g][o2] = (float)Wx[(((size_t)(t + 1) * 64 + b) * 12 + head * 3 + g) * 256 +
                                           o0 + o2 * 16 + c];
        } else {
            wxn[0][0] = wxn[0][1] = wxn[1][0] = wxn[1][1] = wxn[2][0] = wxn[2][1] = 0.f;
        }

        // ---- LDS: loop-invariant B-kt7 frags + pipelined A-frags ----
        f16x8 Bs7[3][2];
#pragma unroll
        for (int g = 0; g < 3; g++)
#pragma unroll
            for (int ot = 0; ot < 2; ot++)
                Bs7[g][ot] =
                    *(const f16x8*)(Rbuf + ((size_t)(g * 256 + o0 + ot * 16 + c)) * 40 + kq * 8);
        f16x8 Af0 = *(const f16x8*)(hc + 0 * 32 + kq * 8);

        f32x4 acc[3][2];
#pragma unroll
        for (int g = 0; g < 3; g++)
#pragma unroll
            for (int ot = 0; ot < 2; ot++) acc[g][ot] = (f32x4){0.f, 0.f, 0.f, 0.f};

#pragma unroll
        for (int kt = 0; kt < 8; kt++) {
            f16x8 Af1;
            if (kt < 7) Af1 = *(const f16x8*)(hc + (kt + 1) * 32 + kq * 8);
#pragma unroll
            for (int g = 0; g < 3; g++)
#pragma unroll
                for (int ot = 0; ot < 2; ot++)
                    acc[g][ot] = __builtin_amdgcn_mfma_f32_16x16x32_f16(
                        Af0, (kt < 7) ? Bf[g][ot][kt] : Bs7[g][ot], acc[g][ot], 0, 0, 0);
            Af0 = Af1;
        }

        // ---- gates (lane-replicated); h kept in regs, LDS write only ----
        _Float16* hw = h16 + (cur ^ 1) * 256;
#pragma unroll
        for (int o2 = 0; o2 < 2; o2++) {
            const float z = sigmoidf_(wxc[0][o2] + acc[0][o2][0]);
            const float r = sigmoidf_(wxc[1][o2] + acc[1][o2][0]);
            const float n = tanhf_(wxc[2][o2] + r * acc[2][o2][0]);
            const float h = n + z * (hprev[o2] - n);
            hprev[o2] = h;
            if (kq == 0) hw[o0 + o2 * 16 + c] = (_Float16)h;
        }
#pragma unroll
        for (int g = 0; g < 3; g++)
#pragma unroll
            for (int o2 = 0; o2 < 2; o2++) wxc[g][o2] = wxn[g][o2];

        __syncthreads();
        cur ^= 1;
    }
    // final stores: h(511) + hn
    if (kq == 0) {
#pragma unroll
        for (int o2 = 0; o2 < 2; o2++) {
            outb[(size_t)511 * 1024 + o0 + o2 * 16 + c] = hprev[o2];
            hnp[o0 + o2 * 16 + c] = hprev[o2];
        }
    }
}

extern "C" void kernel_launch(void* const* d_in, const int* in_sizes, int n_in,
                              void* d_out, int out_size, void* d_ws, size_t ws_size,
                              hipStream_t stream) {
    (void)in_sizes; (void)n_in; (void)out_size; (void)ws_size;
    const float* inp = (const float*)d_in[0];
    const float* W   = (const float*)d_in[1];
    const float* bW  = (const float*)d_in[2];
    const float* R   = (const float*)d_in[3];
    const float* bR  = (const float*)d_in[4];
    float* out = (float*)d_out;

    // ws layout: A16 (64 MiB) | WT (6 MiB) | Wx f16 (192 MiB)
    _Float16* A16 = (_Float16*)d_ws;
    _Float16* WT  = (_Float16*)((char*)d_ws + 67108864);
    _Float16* Wx  = (_Float16*)((char*)d_ws + 73400320);

    cast_to_f16<<<16384, 256, 0, stream>>>(inp, A16, 4194304);
    transpose_cast<<<dim3(96, 32), dim3(32, 8), 0, stream>>>(W, WT);
    gemm_wx<<<dim3(24, 256), 256, 0, stream>>>(A16, WT, bW, bR, Wx);
    scan_mfma<<<256, 512, 0, stream>>>(R, Wx, out);
}